// Round 1
// 1142.103 us; speedup vs baseline: 1.4981x; 1.4981x over previous
//
#include <hip/hip_runtime.h>

// Hete_MLP2_atten: fused  tanh(x@W1+b1)@W2 -> softmax over m -> weighted sum
// M=8 meta paths, D=256, H=128; N from in_sizes[0].
// One wave = 16 nodes (MFMA 16x16x32 bf16 A-rows). Online exp-weighted
// accumulation over m (no max subtraction: |logit| <= sum|W2| ~ 9).
// b2 dropped (cancels in softmax).
//
// R1 change vs baseline (892 us/dispatch, WRITE_SIZE 5x ideal => VGPR spills):
//  - explicit amdgpu_waves_per_eu(2,2): LDS (65.5 KB) caps us at 2 blocks/CU
//    = 2 waves/EU anyway, so the full 256-VGPR/wave budget is free. Baseline
//    allocator targeted 128 VGPRs vs ~216 live => massive scratch traffic.
//  - acch halved (two passes of 4 h-column groups, #pragma unroll 1): 32->16 regs
//  - b1/W2 per-lane values moved to LDS (frees 16 regs, allows runtime th index)
//  - x-tile converted to bf16 at iteration END: loop-carried state is a(32)+acc(64),
//    not fp32 xf(64). Peak live ~200 < 256.
// Numerics identical to baseline (same bf16 RNE, same accumulation order).

typedef __attribute__((ext_vector_type(8))) short short8;
typedef __attribute__((ext_vector_type(4))) int   int4v;
typedef __attribute__((ext_vector_type(4))) float f32x4;

#define DDIM  256
#define HDIM  128
#define MMETA 8

// fp32 -> bf16 round-to-nearest-even, pure integer ops
__device__ __forceinline__ unsigned f2bf_u(float f) {
    unsigned u = __builtin_bit_cast(unsigned, f);
    u += 0x7fffu + ((u >> 16) & 1u);
    return u >> 16;
}
__device__ __forceinline__ unsigned pk2bf(float a, float b) {
    return f2bf_u(a) | (f2bf_u(b) << 16);
}
__device__ __forceinline__ float bf2f(short s) {
    unsigned u = ((unsigned)(unsigned short)s) << 16;
    return __builtin_bit_cast(float, u);
}

__global__
__attribute__((amdgpu_flat_work_group_size(256, 256)))
__attribute__((amdgpu_waves_per_eu(2, 2)))
void hete_mlp2_atten_kernel(
    const float* __restrict__ homo,  // [M,N,D]
    const float* __restrict__ W1,    // [D,H] row-major (h contiguous)
    const float* __restrict__ b1,    // [H]
    const float* __restrict__ W2,    // [H]
    float* __restrict__ out,         // [N,D]
    int N)
{
    // W1 bf16 frags, frag-ordered: chunk c=t*8+s, lane l holds
    // B[k = s*32 + (l>>4)*8 + j][h = t*16 + (l&15)], j=0..7 (16B per lane)
    __shared__ __attribute__((aligned(16))) short w1f[64 * 64 * 8]; // 64 KB
    __shared__ float b1s[HDIM];
    __shared__ float w2s[HDIM];

    const int tid  = threadIdx.x;
    const int lane = tid & 63;
    const int wave = tid >> 6;
    const int colq = lane & 15;   // A-row (node) for loads; h-col in C layout
    const int quad = lane >> 4;

    const int  node   = blockIdx.x * 64 + wave * 16 + colq;
    const bool valid  = node < N;
    const int  nclamp = valid ? node : (N - 1);

    const size_t mstride = (size_t)N * DDIM;
    const float* xp0 = homo + (size_t)nclamp * DDIM + quad * 8;

    // issue first x-tile loads early (independent of LDS fill)
    float4 xf[16];
#pragma unroll
    for (int s = 0; s < 8; ++s) {
        xf[2*s]   = *(const float4*)(xp0 + s*32);
        xf[2*s+1] = *(const float4*)(xp0 + s*32 + 4);
    }

    // bias / W2 into LDS (read per h-group inside the loop; 16 same-addr
    // broadcast lanes per read, conflict-free)
    if (tid < HDIM) {
        b1s[tid] = b1[tid];
        w2s[tid] = W2[tid];
    }

    // ---- build W1 bf16 frags in LDS (once per block) ----
    // wave w handles chunks c == w (mod 4); reads are 64B-line coalesced
    {
#pragma unroll
        for (int i = 0; i < 16; ++i) {
            int c = wave + i*4;
            int t = c >> 3, s = c & 7;
            int k0 = s*32 + quad*8;
            int h  = t*16 + colq;
            const float* wp = W1 + (size_t)k0 * HDIM + h;
            float v[8];
#pragma unroll
            for (int j = 0; j < 8; ++j) v[j] = wp[j * HDIM];
            int4v p;
            p.x = (int)pk2bf(v[0], v[1]); p.y = (int)pk2bf(v[2], v[3]);
            p.z = (int)pk2bf(v[4], v[5]); p.w = (int)pk2bf(v[6], v[7]);
            *(int4v*)&w1f[(c*64 + lane)*8] = p;   // ds_write_b128, conflict-free
        }
    }
    __syncthreads();

    const short* wbase = &w1f[lane * 8];
    const float* b1p = &b1s[colq];
    const float* w2p = &w2s[colq];

    // convert first x-tile to bf16 A-frags (waits on the prologue loads)
    short8 a[8];
#pragma unroll
    for (int s = 0; s < 8; ++s) {
        int4v p;
        float4 lo = xf[2*s], hi = xf[2*s+1];
        p.x = (int)pk2bf(lo.x, lo.y); p.y = (int)pk2bf(lo.z, lo.w);
        p.z = (int)pk2bf(hi.x, hi.y); p.w = (int)pk2bf(hi.z, hi.w);
        a[s] = __builtin_bit_cast(short8, p);
    }

    float acc[64];        // node = colq, d = s*32 + quad*8 + j
#pragma unroll
    for (int i = 0; i < 64; ++i) acc[i] = 0.f;
    float S = 0.f;

#pragma unroll 1
    for (int m = 0; m < MMETA; ++m) {
        // prefetch next m's x-tile (in flight across MFMA/tanh/acc phases)
        if (m + 1 < MMETA) {
            const float* xn = xp0 + (size_t)(m + 1) * mstride;
#pragma unroll
            for (int s = 0; s < 8; ++s) {
                xf[2*s]   = *(const float4*)(xn + s*32);
                xf[2*s+1] = *(const float4*)(xn + s*32 + 4);
            }
        }
        // h = x @ W1 : [16 nodes x 128 h], K=256 in 8 steps.
        // Two halves of 4 h-groups each: acch is 16 regs, not 32.
        float pr[4] = {0.f, 0.f, 0.f, 0.f};
#pragma unroll 1
        for (int th = 0; th < 2; ++th) {
            f32x4 acch[4];
#pragma unroll
            for (int tt = 0; tt < 4; ++tt) acch[tt] = (f32x4){0.f, 0.f, 0.f, 0.f};
#pragma unroll
            for (int s = 0; s < 8; ++s) {
#pragma unroll
                for (int tt = 0; tt < 4; ++tt) {
                    const int c = (th*4 + tt)*8 + s;
                    short8 bfr = *(const short8*)(wbase + c*512); // ds_read_b128
                    acch[tt] = __builtin_amdgcn_mfma_f32_16x16x32_bf16(a[s], bfr, acch[tt], 0, 0, 0);
                }
            }
            // tanh(h + b1) . W2 -> partial logits; C layout: row(node)=quad*4+r, col(h)=colq
#pragma unroll
            for (int tt = 0; tt < 4; ++tt) {
                float b1t = b1p[(th*4 + tt)*16];
                float w2t = w2p[(th*4 + tt)*16];
#pragma unroll
                for (int r = 0; r < 4; ++r) {
                    float v = acch[tt][r] + b1t;
                    v = fminf(fmaxf(v, -15.f), 15.f);       // guard exp overflow -> NaN
                    float e   = __expf(2.f * v);
                    float tnh = (e - 1.f) * __builtin_amdgcn_rcpf(e + 1.f);
                    pr[r] = fmaf(tnh, w2t, pr[r]);
                }
            }
        }
        // reduce over 16 h-col lanes within each quad (xor butterfly)
#pragma unroll
        for (int mask = 1; mask <= 8; mask <<= 1) {
#pragma unroll
            for (int r = 0; r < 4; ++r) pr[r] += __shfl_xor(pr[r], mask);
        }
        // redistribute: lane needs logit of node v=colq; donor lane (v>>2)*16 + (v&3)
        const int l3 = lane & 3;
        float p01 = (l3 & 1) ? pr[1] : pr[0];
        float p23 = (l3 & 1) ? pr[3] : pr[2];
        float expose = (l3 & 2) ? p23 : p01;     // = pr[lane&3]
        float logit  = __shfl(expose, ((lane >> 2) & 3) * 16 + l3);
        float w = __expf(logit);                 // no max-sub: |logit| <= ~9
        S += w;
        // acc += w * x_m  (bf16 x, fp32 acc)
#pragma unroll
        for (int s = 0; s < 8; ++s) {
#pragma unroll
            for (int j = 0; j < 8; ++j) {
                acc[s*8 + j] = fmaf(w, bf2f(a[s][j]), acc[s*8 + j]);
            }
        }
        // convert prefetched tile to bf16 at iteration end: fp32 xf is not
        // loop-carried; only a(32)+acc(64) cross the backedge.
        if (m + 1 < MMETA) {
#pragma unroll
            for (int s = 0; s < 8; ++s) {
                int4v p;
                float4 lo = xf[2*s], hi = xf[2*s+1];
                p.x = (int)pk2bf(lo.x, lo.y); p.y = (int)pk2bf(lo.z, lo.w);
                p.z = (int)pk2bf(hi.x, hi.y); p.w = (int)pk2bf(hi.z, hi.w);
                a[s] = __builtin_bit_cast(short8, p);
            }
        }
    }

    if (valid) {
        float rinv = 1.f / S;
        float* op = out + (size_t)node * DDIM + quad * 8;
#pragma unroll
        for (int s = 0; s < 8; ++s) {
            float4 o0, o1;
            o0.x = acc[s*8+0]*rinv; o0.y = acc[s*8+1]*rinv;
            o0.z = acc[s*8+2]*rinv; o0.w = acc[s*8+3]*rinv;
            o1.x = acc[s*8+4]*rinv; o1.y = acc[s*8+5]*rinv;
            o1.z = acc[s*8+6]*rinv; o1.w = acc[s*8+7]*rinv;
            *(float4*)(op + s*32)     = o0;
            *(float4*)(op + s*32 + 4) = o1;
        }
    }
}

extern "C" void kernel_launch(void* const* d_in, const int* in_sizes, int n_in,
                              void* d_out, int out_size, void* d_ws, size_t ws_size,
                              hipStream_t stream) {
    // inputs: 0=nodes(int32,N, unused) 1=homo(f32,M*N*D) 2=W1(f32,D*H)
    //         3=b1(f32,H) 4=W2(f32,H) 5=b2(f32,1, cancels in softmax)
    const float* homo = (const float*)d_in[1];
    const float* W1   = (const float*)d_in[2];
    const float* b1   = (const float*)d_in[3];
    const float* W2   = (const float*)d_in[4];
    float* out = (float*)d_out;
    const int N = in_sizes[0];
    const int grid = (N + 63) / 64;   // 64 nodes per 256-thread block (16/wave)
    hipLaunchKernelGGL(hete_mlp2_atten_kernel, dim3(grid), dim3(256), 0, stream,
                       homo, W1, b1, W2, out, N);
}

// Round 2
// 1104.356 us; speedup vs baseline: 1.5493x; 1.0342x over previous
//
#include <hip/hip_runtime.h>

// Hete_MLP2_atten: fused  tanh(x@W1+b1)@W2 -> softmax over m -> weighted sum
// M=8 meta paths, D=256, H=128; N from in_sizes[0].
//
// R2 restructure (R1 was ~323 us/dispatch, 8 waves/CU, latency-bound):
//   - block = 512 threads / 8 waves, covers 16 nodes.
//   - x tile (16 nodes x 256 d, bf16) staged in LDS once per m, shared by all
//     waves; XOR-swizzled 16B chunks (col ^ (row&7)) -> conflict-free
//     ds_read_b128 A-frags; double-buffered (2 x 8 KB).
//   - h split across waves: wave w owns h-group [w*16, w*16+16); its W1 slice
//     lives in 32 VGPRs (loaded once from L2-hot W1). No W1 in LDS (was 64 KB).
//   - tanh is elementwise in h => only 16-float logit partials cross waves
//     (tiny LDS buffer, double-buffered against 1-barrier skew).
//   - each thread stages exactly the 8 x-values it accumulates => acc phase
//     uses the staging registers, acc = 8 VGPRs (was 64).
//   Live VGPRs ~90 -> waves_per_eu(4,4): 16 waves/CU (2x R1), LDS 17 KB.
// Numerics: same bf16 RNE, same MFMA K-order, same per-d accumulation order
// over m; logit sum re-associates (sum_t sum_lanes) ~1e-6 relative only.

typedef __attribute__((ext_vector_type(8))) short short8;
typedef __attribute__((ext_vector_type(4))) int   int4v;
typedef __attribute__((ext_vector_type(4))) float f32x4;

#define DDIM  256
#define HDIM  128
#define MMETA 8

// fp32 -> bf16 round-to-nearest-even, pure integer ops
__device__ __forceinline__ unsigned f2bf_u(float f) {
    unsigned u = __builtin_bit_cast(unsigned, f);
    u += 0x7fffu + ((u >> 16) & 1u);
    return u >> 16;
}
__device__ __forceinline__ unsigned pk2bf(float a, float b) {
    return f2bf_u(a) | (f2bf_u(b) << 16);
}
__device__ __forceinline__ float bf2f(short s) {
    unsigned u = ((unsigned)(unsigned short)s) << 16;
    return __builtin_bit_cast(float, u);
}

__global__
__attribute__((amdgpu_flat_work_group_size(512, 512)))
__attribute__((amdgpu_waves_per_eu(4, 4)))
void hete_mlp2_atten_kernel(const float* __restrict__ homo,  // [M,N,D]
                            const float* __restrict__ W1,    // [D,H]
                            const float* __restrict__ b1,    // [H]
                            const float* __restrict__ W2,    // [H]
                            float* __restrict__ out,         // [N,D]
                            int N)
{
    // x tile: row = tile-node (0..15), col = 16B chunk (0..31),
    // shorts offset = row*256 + ((col ^ (row&7)) << 3). Double buffered.
    __shared__ __attribute__((aligned(16))) short xtile[2][16 * 256]; // 16 KB
    __shared__ float logit_p[2][8][16];                               // 1 KB

    const int tid  = threadIdx.x;
    const int lane = tid & 63;
    const int wv   = tid >> 6;     // wave index == h-group t (0..7)
    const int colq = lane & 15;    // MFMA col: h = wv*16 + colq; A-row = node
    const int quad = lane >> 4;

    // staging / output identity: thread owns x[node_s][dc*8 .. dc*8+7]
    const int node_s = tid >> 5;   // 0..15
    const int dc     = tid & 31;   // 16B chunk within the 1 KB row
    const int gnode  = blockIdx.x * 16 + node_s;
    const int gclamp = (gnode < N) ? gnode : (N - 1);
    const float* xs  = homo + (size_t)gclamp * DDIM + dc * 8;
    const size_t mstride = (size_t)N * DDIM;

    // issue first x-tile loads before anything else (HBM latency under W1 fill)
    float4 xr0 = *(const float4*)(xs);
    float4 xr1 = *(const float4*)(xs + 4);

    // B-frags for this wave's h-columns, in registers for the whole kernel:
    // bfr[s] lane l = W1[k = s*32 + (l>>4)*8 + j][h = wv*16 + (l&15)]
    short8 bfr[8];
    {
        const float* wp = W1 + (size_t)(quad * 8) * HDIM + (wv * 16 + colq);
#pragma unroll
        for (int s = 0; s < 8; ++s) {
            const float* w = wp + (size_t)(s * 32) * HDIM;
            float v[8];
#pragma unroll
            for (int j = 0; j < 8; ++j) v[j] = w[(size_t)j * HDIM];
            int4v p;
            p.x = (int)pk2bf(v[0], v[1]); p.y = (int)pk2bf(v[2], v[3]);
            p.z = (int)pk2bf(v[4], v[5]); p.w = (int)pk2bf(v[6], v[7]);
            bfr[s] = __builtin_bit_cast(short8, p);
        }
    }
    const float b1v = b1[wv * 16 + colq];
    const float w2v = W2[wv * 16 + colq];

    const int st_off = node_s * 256 + ((dc ^ (node_s & 7)) << 3); // shorts

    // stage m=0 (thread keeps its own 8 bf16 values for the acc phase)
    short8 own_cur;
    {
        int4v p;
        p.x = (int)pk2bf(xr0.x, xr0.y); p.y = (int)pk2bf(xr0.z, xr0.w);
        p.z = (int)pk2bf(xr1.x, xr1.y); p.w = (int)pk2bf(xr1.z, xr1.w);
        own_cur = __builtin_bit_cast(short8, p);
        *(int4v*)&xtile[0][st_off] = p;
    }
    __syncthreads();

    float acc[8];
#pragma unroll
    for (int j = 0; j < 8; ++j) acc[j] = 0.f;
    float S = 0.f;

    const int   aswz  = colq & 7;
    const short* arow0 = &xtile[0][colq * 256];
    const short* arow1 = &xtile[1][colq * 256];

    int cur = 0;
#pragma unroll 1
    for (int m = 0; m < MMETA; ++m) {
        // prefetch next m's x values (in flight across MFMA/tanh phases)
        if (m + 1 < MMETA) {
            const float* xn = xs + (size_t)(m + 1) * mstride;
            xr0 = *(const float4*)(xn);
            xr1 = *(const float4*)(xn + 4);
        }
        // h = x @ W1 for this wave's 16 h-cols, K=256 in 8 MFMAs
        const short* ap = cur ? arow1 : arow0;
        f32x4 acch = (f32x4){0.f, 0.f, 0.f, 0.f};
#pragma unroll
        for (int s = 0; s < 8; ++s) {
            short8 a = *(const short8*)(ap + (((s * 4 + quad) ^ aswz) << 3));
            acch = __builtin_amdgcn_mfma_f32_16x16x32_bf16(a, bfr[s], acch, 0, 0, 0);
        }
        // tanh(h + b1) * W2 -> reduce over the 16 h-col lanes of each quad
        float pr[4];
#pragma unroll
        for (int r = 0; r < 4; ++r) {
            float v = acch[r] + b1v;
            v = fminf(fmaxf(v, -15.f), 15.f);        // guard exp overflow
            float e  = __expf(2.f * v);
            float th = (e - 1.f) * __builtin_amdgcn_rcpf(e + 1.f);
            pr[r] = th * w2v;
        }
#pragma unroll
        for (int mask = 1; mask <= 8; mask <<= 1) {
#pragma unroll
            for (int r = 0; r < 4; ++r) pr[r] += __shfl_xor(pr[r], mask);
        }
        // publish this wave's 16-h partial logits (nodes quad*4+r)
        if (colq == 0) {
            logit_p[m & 1][wv][quad * 4 + 0] = pr[0];
            logit_p[m & 1][wv][quad * 4 + 1] = pr[1];
            logit_p[m & 1][wv][quad * 4 + 2] = pr[2];
            logit_p[m & 1][wv][quad * 4 + 3] = pr[3];
        }
        // stage next tile into the other buffer
        short8 own_next = own_cur;
        if (m + 1 < MMETA) {
            int4v p;
            p.x = (int)pk2bf(xr0.x, xr0.y); p.y = (int)pk2bf(xr0.z, xr0.w);
            p.z = (int)pk2bf(xr1.x, xr1.y); p.w = (int)pk2bf(xr1.z, xr1.w);
            own_next = __builtin_bit_cast(short8, p);
            *(int4v*)&xtile[cur ^ 1][st_off] = p;
        }
        __syncthreads();
        // full logit for own node -> softmax weight -> accumulate own 8 d
        float lg = 0.f;
#pragma unroll
        for (int w = 0; w < 8; ++w) lg += logit_p[m & 1][w][node_s];
        float we = __expf(lg);                       // no max-sub: |logit| <~ 9
        S += we;
#pragma unroll
        for (int j = 0; j < 8; ++j)
            acc[j] = fmaf(we, bf2f(own_cur[j]), acc[j]);
        own_cur = own_next;
        cur ^= 1;
    }

    if (gnode < N) {
        float rinv = 1.f / S;
        float* op = out + (size_t)gnode * DDIM + dc * 8;
        float4 o0, o1;
        o0.x = acc[0] * rinv; o0.y = acc[1] * rinv;
        o0.z = acc[2] * rinv; o0.w = acc[3] * rinv;
        o1.x = acc[4] * rinv; o1.y = acc[5] * rinv;
        o1.z = acc[6] * rinv; o1.w = acc[7] * rinv;
        *(float4*)(op)     = o0;
        *(float4*)(op + 4) = o1;
    }
}

extern "C" void kernel_launch(void* const* d_in, const int* in_sizes, int n_in,
                              void* d_out, int out_size, void* d_ws, size_t ws_size,
                              hipStream_t stream) {
    // inputs: 0=nodes(int32,N, unused) 1=homo(f32,M*N*D) 2=W1(f32,D*H)
    //         3=b1(f32,H) 4=W2(f32,H) 5=b2(f32,1, cancels in softmax)
    const float* homo = (const float*)d_in[1];
    const float* W1   = (const float*)d_in[2];
    const float* b1   = (const float*)d_in[3];
    const float* W2   = (const float*)d_in[4];
    float* out = (float*)d_out;
    const int N = in_sizes[0];
    const int grid = (N + 15) / 16;   // 16 nodes per 512-thread block
    hipLaunchKernelGGL(hete_mlp2_atten_kernel, dim3(grid), dim3(512), 0, stream,
                       homo, W1, b1, W2, out, N);
}